// Round 1
// baseline (271.078 us; speedup 1.0000x reference)
//
#include <hip/hip_runtime.h>

typedef __attribute__((ext_vector_type(8))) short short8;
typedef __attribute__((ext_vector_type(4))) float f32x4;

#define DEV static __device__ __forceinline__

DEV unsigned short f2bf(float f) {
  unsigned int u = __float_as_uint(f);
  u += 0x7fff + ((u >> 16) & 1);   // RNE
  return (unsigned short)(u >> 16);
}

DEV f32x4 mfma16(short8 a, short8 b, f32x4 c) {
  return __builtin_amdgcn_mfma_f32_16x16x32_bf16(a, b, c, 0, 0, 0);
}

// ---------------------------------------------------------------------------
// Wrp = Wr @ Wo  (2 x 1024), split over 16 e-chunks for parallelism
// ---------------------------------------------------------------------------
__global__ __launch_bounds__(256) void wrp_partial(const float* __restrict__ Wr,
                                                   const float* __restrict__ Wo,
                                                   float* __restrict__ part) {
  int blk = blockIdx.x;        // 16 blocks, each 64 e's
  int tid = threadIdx.x;       // 256 threads, each 4 j's
  float a0[4] = {0.f,0.f,0.f,0.f};
  float a1[4] = {0.f,0.f,0.f,0.f};
  int e0 = blk * 64;
  for (int e = e0; e < e0 + 64; e++) {
    float w0 = Wr[e];
    float w1 = Wr[1024 + e];
    #pragma unroll
    for (int j4 = 0; j4 < 4; j4++) {
      float wo = Wo[(size_t)e * 1024 + j4 * 256 + tid];
      a0[j4] += w0 * wo;
      a1[j4] += w1 * wo;
    }
  }
  #pragma unroll
  for (int j4 = 0; j4 < 4; j4++) {
    part[blk * 2048 + 0    + j4 * 256 + tid] = a0[j4];
    part[blk * 2048 + 1024 + j4 * 256 + tid] = a1[j4];
  }
}

__global__ __launch_bounds__(256) void wrp_reduce(const float* __restrict__ part,
                                                  float* __restrict__ Wrp) {
  int id = blockIdx.x * 256 + threadIdx.x;   // 2048
  float s = 0.f;
  #pragma unroll
  for (int blk = 0; blk < 16; blk++) s += part[blk * 2048 + id];
  Wrp[id] = s;
}

// ---------------------------------------------------------------------------
// Tiled bf16 MFMA GEMM, C = A @ B^T.  A fp32 (M x 1024), B fp32 (N x 1024).
// 128x128 block tile, BK=32, 4 waves (2x2), each wave 64x64 (4x4 frags).
// MODE 0: q projection -> fp32 out (256 x 1024)
// MODE 1: fused k/v projection -> k bf16 (B,KV,K,D), v bf16 TRANSPOSED (B,KV,D,K)
// LDS layout [khi][row][8] so frag ds_read_b128 is conflict-free.
// ---------------------------------------------------------------------------
template <int MODE>
__global__ __launch_bounds__(256) void gemm_bt(const float* __restrict__ A,
                                               const float* __restrict__ B0,
                                               const float* __restrict__ B1,
                                               unsigned short* __restrict__ ok,
                                               unsigned short* __restrict__ ov,
                                               float* __restrict__ of) {
  __shared__ unsigned short Al[2][4096];
  __shared__ unsigned short Bl[2][4096];

  int bid = blockIdx.x;
  int mb, nb;
  if (MODE == 0) { mb = bid >> 3; nb = bid & 7; }          // 2 x 8
  else {                                                    // 256 x 4, XCD swizzle
    int swz = (bid & 7) * 128 + (bid >> 3);
    mb = swz >> 2; nb = swz & 3;
  }
  int m0 = mb * 128, n0 = nb * 128;

  int tid = threadIdx.x;
  int w = tid >> 6, l = tid & 63;
  int l4 = l >> 4, l15 = l & 15;
  int wm = w >> 1, wn = w & 1;

  // staging: thread -> row (tid>>1), 16 k's at offset (tid&1)*16
  int sm = tid >> 1;
  int kh0 = (tid & 1) * 2;
  const float* ap = A + (size_t)(m0 + sm) * 1024 + (tid & 1) * 16;
  const float* bp;
  if (MODE == 0) {
    bp = B0 + (size_t)(n0 + sm) * 1024 + (tid & 1) * 16;
  } else {
    int n = n0 + sm;
    bp = (n < 256 ? B0 + (size_t)n * 1024 : B1 + (size_t)(n - 256) * 1024) + (tid & 1) * 16;
  }

  f32x4 acc[4][4];
  #pragma unroll
  for (int i = 0; i < 4; i++)
    #pragma unroll
    for (int j = 0; j < 4; j++) acc[i][j] = (f32x4)(0.f);

  float fa[16], fb[16];

  #define LD_STEP(kstep)                                                   \
    {                                                                      \
      _Pragma("unroll")                                                    \
      for (int i = 0; i < 4; i++) {                                        \
        float4 ta = *(const float4*)(ap + (kstep) * 32 + i * 4);           \
        float4 tb = *(const float4*)(bp + (kstep) * 32 + i * 4);           \
        fa[4*i+0]=ta.x; fa[4*i+1]=ta.y; fa[4*i+2]=ta.z; fa[4*i+3]=ta.w;    \
        fb[4*i+0]=tb.x; fb[4*i+1]=tb.y; fb[4*i+2]=tb.z; fb[4*i+3]=tb.w;    \
      }                                                                    \
    }

  #define ST_STEP(bufi)                                                    \
    {                                                                      \
      short8 v0, v1, u0, u1;                                               \
      _Pragma("unroll")                                                    \
      for (int i = 0; i < 8; i++) {                                        \
        v0[i] = (short)f2bf(fa[i]); v1[i] = (short)f2bf(fa[8 + i]);        \
        u0[i] = (short)f2bf(fb[i]); u1[i] = (short)f2bf(fb[8 + i]);        \
      }                                                                    \
      *(short8*)&Al[bufi][((kh0 + 0) * 128 + sm) * 8] = v0;                \
      *(short8*)&Al[bufi][((kh0 + 1) * 128 + sm) * 8] = v1;                \
      *(short8*)&Bl[bufi][((kh0 + 0) * 128 + sm) * 8] = u0;                \
      *(short8*)&Bl[bufi][((kh0 + 1) * 128 + sm) * 8] = u1;                \
    }

  LD_STEP(0);
  ST_STEP(0);
  __syncthreads();

  for (int t = 0; t < 32; t++) {
    int buf = t & 1;
    if (t + 1 < 32) LD_STEP(t + 1);

    short8 af[4], bf[4];
    #pragma unroll
    for (int i = 0; i < 4; i++)
      af[i] = *(const short8*)&Al[buf][(l4 * 128 + wm * 64 + i * 16 + l15) * 8];
    #pragma unroll
    for (int j = 0; j < 4; j++)
      bf[j] = *(const short8*)&Bl[buf][(l4 * 128 + wn * 64 + j * 16 + l15) * 8];
    #pragma unroll
    for (int i = 0; i < 4; i++)
      #pragma unroll
      for (int j = 0; j < 4; j++)
        acc[i][j] = mfma16(af[i], bf[j], acc[i][j]);

    if (t + 1 < 32) ST_STEP(buf ^ 1);
    __syncthreads();
  }
  #undef LD_STEP
  #undef ST_STEP

  if (MODE == 0) {
    #pragma unroll
    for (int i = 0; i < 4; i++)
      #pragma unroll
      for (int j = 0; j < 4; j++) {
        int n = n0 + wn * 64 + j * 16 + l15;
        #pragma unroll
        for (int r = 0; r < 4; r++) {
          int m = m0 + wm * 64 + i * 16 + l4 * 4 + r;
          of[(size_t)m * 1024 + n] = acc[i][j][r];
        }
      }
  } else {
    #pragma unroll
    for (int i = 0; i < 4; i++)
      #pragma unroll
      for (int j = 0; j < 4; j++) {
        int n = n0 + wn * 64 + j * 16 + l15;
        int kvv = n >> 6, d = n & 63;
        #pragma unroll
        for (int r = 0; r < 4; r++) {
          int m = m0 + wm * 64 + i * 16 + l4 * 4 + r;
          int bb = m >> 11, kk = m & 2047;
          unsigned short val = f2bf(acc[i][j][r]);
          if (kvv < 4)
            ok[((size_t)(bb * 4 + kvv) * 2048 + kk) * 64 + d] = val;           // (B,KV,K,D)
          else
            ov[((size_t)(bb * 4 + (kvv - 4)) * 64 + d) * 2048 + kk] = val;     // (B,KV,D,K)
        }
      }
  }
}

// ---------------------------------------------------------------------------
// RoPE on q + scale by 1/sqrt(64)*log2(e), write bf16 as (H, BIN, D)
// ---------------------------------------------------------------------------
__global__ __launch_bounds__(256) void rope_kernel(const float* __restrict__ qf,
                                                   const float* __restrict__ cosb,
                                                   const float* __restrict__ sinb,
                                                   unsigned short* __restrict__ qb) {
  int id = blockIdx.x * 256 + threadIdx.x;   // 262144
  int qrow = id >> 10, hd = id & 1023, hh = hd >> 6, d = hd & 63;
  float v = qf[qrow * 1024 + hd];
  float c = cosb[qrow * 64 + d];
  float s = sinb[qrow * 64 + d];
  float other = (d < 32) ? -qf[qrow * 1024 + hh * 64 + d + 32]
                         :  qf[qrow * 1024 + hh * 64 + d - 32];
  float outv = (v * c + other * s) * 0.18033688011112042f;  // 0.125 * log2(e)
  qb[((size_t)hh * 256 + qrow) * 64 + d] = f2bf(outv);
}

// ---------------------------------------------------------------------------
// Flash attention, one block per (b, h, q-half). 4 waves x 32 q-rows.
// K tile (64x64) and V^T tile (64x64) staged in LDS (XOR-swizzled),
// P round-trips per-warp LDS. exp2-domain online softmax.
// Epilogue folds Wo/Wr: writes per-head partial (B,H,BIN,2).
// ---------------------------------------------------------------------------
__global__ __launch_bounds__(256) void attn_kernel(const unsigned short* __restrict__ qb,
                                                   const unsigned short* __restrict__ kb,
                                                   const unsigned short* __restrict__ vb,
                                                   const float* __restrict__ Wrp,
                                                   float* __restrict__ part) {
  __shared__ unsigned short Kt[2][4096];
  __shared__ unsigned short Vt[2][4096];
  __shared__ unsigned short Pl[4][2048];

  int bid = blockIdx.x;
  int vidx = (bid & 7) * 64 + (bid >> 3);     // XCD swizzle (512 = 8*64)
  int b = vidx >> 5, h = (vidx >> 1) & 15, qh = vidx & 1;
  int kvh = h >> 2;

  int tid = threadIdx.x;
  int w = tid >> 6, l = tid & 63;
  int l4 = l >> 4, l15 = l & 15;
  int q0 = qh * 128 + w * 32;

  const unsigned short* kg = kb + (size_t)(b * 4 + kvh) * 2048 * 64;
  const unsigned short* vg = vb + (size_t)(b * 4 + kvh) * 64 * 2048;

  // Q fragments (A-operand): row = l15, k = l4*8..+8
  short8 qf[2][2];
  #pragma unroll
  for (int fr = 0; fr < 2; fr++)
    #pragma unroll
    for (int ks = 0; ks < 2; ks++)
      qf[fr][ks] = *(const short8*)&qb[((size_t)h * 256 + q0 + fr * 16 + l15) * 64 + ks * 32 + l4 * 8];

  f32x4 O[2][4];
  #pragma unroll
  for (int fr = 0; fr < 2; fr++)
    #pragma unroll
    for (int fc = 0; fc < 4; fc++) O[fr][fc] = (f32x4)(0.f);
  float mrun[2][4], lrun[2][4];
  #pragma unroll
  for (int fr = 0; fr < 2; fr++)
    #pragma unroll
    for (int r = 0; r < 4; r++) { mrun[fr][r] = -1e30f; lrun[fr][r] = 0.f; }

  int srow = tid >> 2, sseg = tid & 3;
  int wb0 = srow * 128 + ((sseg * 32)      ^ ((srow & 7) << 4));
  int wb1 = srow * 128 + ((sseg * 32 + 16) ^ ((srow & 7) << 4));

  short8 k0r, k1r, v0r, v1r;
  {
    const unsigned short* ksrc = kg + srow * 64 + sseg * 16;
    const unsigned short* vsrc = vg + (size_t)srow * 2048 + sseg * 16;
    k0r = *(const short8*)(ksrc);     k1r = *(const short8*)(ksrc + 8);
    v0r = *(const short8*)(vsrc);     v1r = *(const short8*)(vsrc + 8);
    *(short8*)((char*)Kt[0] + wb0) = k0r;  *(short8*)((char*)Kt[0] + wb1) = k1r;
    *(short8*)((char*)Vt[0] + wb0) = v0r;  *(short8*)((char*)Vt[0] + wb1) = v1r;
  }

  for (int step = 0; step < 32; step++) {
    int buf = step & 1;
    __syncthreads();

    if (step + 1 < 32) {   // issue next tile's global loads early (T14)
      int kk = (step + 1) * 64;
      const unsigned short* ksrc = kg + (size_t)(kk + srow) * 64 + sseg * 16;
      const unsigned short* vsrc = vg + (size_t)srow * 2048 + kk + sseg * 16;
      k0r = *(const short8*)(ksrc);  k1r = *(const short8*)(ksrc + 8);
      v0r = *(const short8*)(vsrc);  v1r = *(const short8*)(vsrc + 8);
    }

    // S = Q K^T  (32 x 64)
    f32x4 S[2][4];
    #pragma unroll
    for (int fr = 0; fr < 2; fr++)
      #pragma unroll
      for (int fc = 0; fc < 4; fc++) S[fr][fc] = (f32x4)(0.f);
    #pragma unroll
    for (int ks = 0; ks < 2; ks++) {
      short8 kf[4];
      #pragma unroll
      for (int fc = 0; fc < 4; fc++) {
        int row = fc * 16 + l15;
        int byt = row * 128 + (((ks * 64) + l4 * 16) ^ ((row & 7) << 4));
        kf[fc] = *(const short8*)((char*)Kt[buf] + byt);
      }
      #pragma unroll
      for (int fr = 0; fr < 2; fr++)
        #pragma unroll
        for (int fc = 0; fc < 4; fc++)
          S[fr][fc] = mfma16(qf[fr][ks], kf[fc], S[fr][fc]);
    }

    // online softmax (exp2 domain; log2e folded into q scale)
    #pragma unroll
    for (int fr = 0; fr < 2; fr++)
      #pragma unroll
      for (int r = 0; r < 4; r++) {
        float mx = fmaxf(fmaxf(S[fr][0][r], S[fr][1][r]), fmaxf(S[fr][2][r], S[fr][3][r]));
        mx = fmaxf(mx, __shfl_xor(mx, 1));
        mx = fmaxf(mx, __shfl_xor(mx, 2));
        mx = fmaxf(mx, __shfl_xor(mx, 4));
        mx = fmaxf(mx, __shfl_xor(mx, 8));
        float mold = mrun[fr][r];
        float mnew = fmaxf(mold, mx);
        float corr = exp2f(mold - mnew);
        mrun[fr][r] = mnew;
        float ls = lrun[fr][r] * corr;
        int row = fr * 16 + l4 * 4 + r;
        #pragma unroll
        for (int fc = 0; fc < 4; fc++) {
          float p = exp2f(S[fr][fc][r] - mnew);
          ls += p;
          int col = fc * 16 + l15;
          int byt = row * 128 + ((col * 2) ^ ((row & 7) << 4));
          *(unsigned short*)((char*)Pl[w] + byt) = f2bf(p);
          O[fr][fc][r] *= corr;
        }
        lrun[fr][r] = ls;
      }

    // O += P V   (A = P from per-warp LDS, B = V^T tile)
    #pragma unroll
    for (int ks = 0; ks < 2; ks++) {
      short8 pf[2], vf[4];
      #pragma unroll
      for (int fr = 0; fr < 2; fr++) {
        int row = fr * 16 + l15;
        int byt = row * 128 + (((ks * 64) + l4 * 16) ^ ((row & 7) << 4));
        pf[fr] = *(const short8*)((char*)Pl[w] + byt);
      }
      #pragma unroll
      for (int fc = 0; fc < 4; fc++) {
        int row = fc * 16 + l15;
        int byt = row * 128 + (((ks * 64) + l4 * 16) ^ ((row & 7) << 4));
        vf[fc] = *(const short8*)((char*)Vt[buf] + byt);
      }
      #pragma unroll
      for (int fr = 0; fr < 2; fr++)
        #pragma unroll
        for (int fc = 0; fc < 4; fc++)
          O[fr][fc] = mfma16(pf[fr], vf[fc], O[fr][fc]);
    }

    if (step + 1 < 32) {
      int nb2 = buf ^ 1;
      *(short8*)((char*)Kt[nb2] + wb0) = k0r;  *(short8*)((char*)Kt[nb2] + wb1) = k1r;
      *(short8*)((char*)Vt[nb2] + wb0) = v0r;  *(short8*)((char*)Vt[nb2] + wb1) = v1r;
    }
  }

  // finish: reduce l across the 16-lane col groups, normalize, fold Wrp
  float rinv[2][4];
  #pragma unroll
  for (int fr = 0; fr < 2; fr++)
    #pragma unroll
    for (int r = 0; r < 4; r++) {
      float ls = lrun[fr][r];
      ls += __shfl_xor(ls, 1);
      ls += __shfl_xor(ls, 2);
      ls += __shfl_xor(ls, 4);
      ls += __shfl_xor(ls, 8);
      rinv[fr][r] = 1.0f / ls;
    }

  float wc0[4], wc1[4];
  #pragma unroll
  for (int fc = 0; fc < 4; fc++) {
    wc0[fc] = Wrp[h * 64 + fc * 16 + l15];
    wc1[fc] = Wrp[1024 + h * 64 + fc * 16 + l15];
  }

  #pragma unroll
  for (int fr = 0; fr < 2; fr++)
    #pragma unroll
    for (int r = 0; r < 4; r++) {
      float a0 = 0.f, a1 = 0.f;
      #pragma unroll
      for (int fc = 0; fc < 4; fc++) {
        float o = O[fr][fc][r] * rinv[fr][r];
        a0 += o * wc0[fc];
        a1 += o * wc1[fc];
      }
      a0 += __shfl_xor(a0, 1); a0 += __shfl_xor(a0, 2);
      a0 += __shfl_xor(a0, 4); a0 += __shfl_xor(a0, 8);
      a1 += __shfl_xor(a1, 1); a1 += __shfl_xor(a1, 2);
      a1 += __shfl_xor(a1, 4); a1 += __shfl_xor(a1, 8);
      if (l15 == 0) {
        int qrow = q0 + fr * 16 + l4 * 4 + r;
        size_t base = ((size_t)(b * 16 + h) * 256 + qrow) * 2;
        part[base + 0] = a0;
        part[base + 1] = a1;
      }
    }
}

// ---------------------------------------------------------------------------
// out[b,q,c] = br[c] + sum_h part[b,h,q,c]
// ---------------------------------------------------------------------------
__global__ __launch_bounds__(256) void final_kernel(const float* __restrict__ part,
                                                    const float* __restrict__ br,
                                                    float* __restrict__ out) {
  int id = blockIdx.x * 256 + threadIdx.x;   // 8192
  int c = id & 1, q = (id >> 1) & 255, b = id >> 9;
  float s = br[c];
  #pragma unroll
  for (int hh = 0; hh < 16; hh++)
    s += part[(((size_t)(b * 16 + hh) * 256) + q) * 2 + c];
  out[id] = s;
}

// ---------------------------------------------------------------------------
extern "C" void kernel_launch(void* const* d_in, const int* in_sizes, int n_in,
                              void* d_out, int out_size, void* d_ws, size_t ws_size,
                              hipStream_t stream) {
  const float* h    = (const float*)d_in[0];
  const float* fcos = (const float*)d_in[1];
  const float* fsin = (const float*)d_in[2];
  const float* Wq   = (const float*)d_in[3];
  const float* Wk   = (const float*)d_in[4];
  const float* Wv   = (const float*)d_in[5];
  const float* Wo   = (const float*)d_in[6];
  const float* oq   = (const float*)d_in[7];
  const float* Wr   = (const float*)d_in[8];
  const float* br   = (const float*)d_in[9];
  float* out = (float*)d_out;

  char* ws = (char*)d_ws;
  unsigned short* kbuf = (unsigned short*)(ws);                 // 16 MB (B,KV,K,D) bf16
  unsigned short* vbuf = (unsigned short*)(ws + 16777216);      // 16 MB (B,KV,D,K) bf16
  float* qf32          = (float*)(ws + 33554432);               // 1 MB
  unsigned short* qbf  = (unsigned short*)(ws + 34603008);      // 0.5 MB (H,BIN,D) bf16
  float* wpart         = (float*)(ws + 35127296);               // 128 KB
  float* Wrp           = (float*)(ws + 35258368);               // 8 KB
  float* apart         = (float*)(ws + 35266560);               // 512 KB (B,H,BIN,2)

  wrp_partial<<<dim3(16), dim3(256), 0, stream>>>(Wr, Wo, wpart);
  wrp_reduce<<<dim3(8), dim3(256), 0, stream>>>(wpart, Wrp);
  gemm_bt<0><<<dim3(16), dim3(256), 0, stream>>>(oq, Wq, nullptr, nullptr, nullptr, qf32);
  rope_kernel<<<dim3(1024), dim3(256), 0, stream>>>(qf32, fcos, fsin, qbf);
  gemm_bt<1><<<dim3(1024), dim3(256), 0, stream>>>(h, Wk, Wv, kbuf, vbuf, nullptr);
  attn_kernel<<<dim3(512), dim3(256), 0, stream>>>(qbf, kbuf, vbuf, Wrp, apart);
  final_kernel<<<dim3(32), dim3(256), 0, stream>>>(apart, br, out);
}

// Round 3
// 222.457 us; speedup vs baseline: 1.2186x; 1.2186x over previous
//
#include <hip/hip_runtime.h>

typedef __attribute__((ext_vector_type(8))) short short8;
typedef __attribute__((ext_vector_type(4))) float f32x4;

#define DEV static __device__ __forceinline__

DEV unsigned short f2bf(float f) {
  unsigned int u = __float_as_uint(f);
  u += 0x7fff + ((u >> 16) & 1);   // RNE
  return (unsigned short)(u >> 16);
}

DEV unsigned int cvtpk(float lo, float hi) {   // packed f32x2 -> bf16x2 (RNE)
  unsigned int r;
  asm("v_cvt_pk_bf16_f32 %0, %1, %2" : "=v"(r) : "v"(lo), "v"(hi));
  return r;
}

DEV f32x4 mfma16(short8 a, short8 b, f32x4 c) {
  return __builtin_amdgcn_mfma_f32_16x16x32_bf16(a, b, c, 0, 0, 0);
}

DEV void gl_lds16(const void* g, void* l) {
  __builtin_amdgcn_global_load_lds((const __attribute__((address_space(1))) void*)g,
                                   (__attribute__((address_space(3))) void*)l, 16, 0, 0);
}

// ---------------------------------------------------------------------------
// Convert Wq / Wk / Wv fp32 -> bf16 (wqb 1024x1024; wkvb 512x1024, k then v)
// ---------------------------------------------------------------------------
__global__ __launch_bounds__(256) void cvtB_kernel(const float* __restrict__ Wq,
                                                   const float* __restrict__ Wk,
                                                   const float* __restrict__ Wv,
                                                   unsigned short* __restrict__ wqb,
                                                   unsigned short* __restrict__ wkvb) {
  int id = blockIdx.x * 256 + threadIdx.x;   // 393216 threads x 4 elems
  int e = id * 4;
  float4 v;
  unsigned short* d;
  if (e < 1048576)      { v = *(const float4*)(Wq + e);             d = wqb + e; }
  else if (e < 1310720) { v = *(const float4*)(Wk + (e - 1048576)); d = wkvb + (e - 1048576); }
  else                  { v = *(const float4*)(Wv + (e - 1310720)); d = wkvb + 262144 + (e - 1310720); }
  uint2 pk;
  pk.x = cvtpk(v.x, v.y);
  pk.y = cvtpk(v.z, v.w);
  *(uint2*)d = pk;
}

// ---------------------------------------------------------------------------
// Wrp = Wr @ Wo  (2 x 1024)
// ---------------------------------------------------------------------------
__global__ __launch_bounds__(256) void wrp_partial(const float* __restrict__ Wr,
                                                   const float* __restrict__ Wo,
                                                   float* __restrict__ part) {
  int blk = blockIdx.x;
  int tid = threadIdx.x;
  float a0[4] = {0.f,0.f,0.f,0.f};
  float a1[4] = {0.f,0.f,0.f,0.f};
  int e0 = blk * 64;
  for (int e = e0; e < e0 + 64; e++) {
    float w0 = Wr[e];
    float w1 = Wr[1024 + e];
    #pragma unroll
    for (int j4 = 0; j4 < 4; j4++) {
      float wo = Wo[(size_t)e * 1024 + j4 * 256 + tid];
      a0[j4] += w0 * wo;
      a1[j4] += w1 * wo;
    }
  }
  #pragma unroll
  for (int j4 = 0; j4 < 4; j4++) {
    part[blk * 2048 + 0    + j4 * 256 + tid] = a0[j4];
    part[blk * 2048 + 1024 + j4 * 256 + tid] = a1[j4];
  }
}

__global__ __launch_bounds__(256) void wrp_reduce(const float* __restrict__ part,
                                                  float* __restrict__ Wrp) {
  int id = blockIdx.x * 256 + threadIdx.x;
  float s = 0.f;
  #pragma unroll
  for (int blk = 0; blk < 16; blk++) s += part[blk * 2048 + id];
  Wrp[id] = s;
}

// ---------------------------------------------------------------------------
// MFMA GEMM, C = A(fp32) @ Bb(bf16)^T.  128x128 tile, BK=32, 4 waves (2x2).
// A staged fp32 into LDS via global_load_lds with XOR-16B swizzle realized by
// permuting the per-lane GLOBAL source (LDS dest linear). bf16 cvt happens at
// fragment build via v_cvt_pk_bf16_f32. B staged bf16 via global_load_lds.
// MODE 0: q projection, 4-way K-split -> of[s][256][1024] fp32 partials
// MODE 1: fused k/v projection -> ok bf16 (B,KV,K,D), ov bf16 (B,KV,D,K)
// ---------------------------------------------------------------------------
template <int MODE>
__global__ __launch_bounds__(256) void gemm_f(const float* __restrict__ A,
                                              const unsigned short* __restrict__ Bb,
                                              unsigned short* __restrict__ ok,
                                              unsigned short* __restrict__ ov,
                                              float* __restrict__ of) {
  __shared__ char Asm[2][16384];   // [row(128)][16B-unit u(8)], u = k16 ^ (row&7)
  __shared__ char Bsm[2][8192];    // [row(128)][k(32) bf16] linear

  int bid = blockIdx.x;
  int m0, n0, t0, ksplit = 0;
  constexpr int nt = (MODE == 0) ? 8 : 32;
  if (MODE == 0) {
    ksplit = bid >> 4;
    m0 = ((bid >> 3) & 1) * 128;
    n0 = (bid & 7) * 128;
    t0 = ksplit * 8;
  } else {
    int swz = (bid & 7) * 128 + (bid >> 3);   // XCD swizzle
    m0 = (swz >> 2) * 128;
    n0 = (swz & 3) * 128;
    t0 = 0;
  }

  int tid = threadIdx.x;
  int w = tid >> 6, l = tid & 63;
  int l4 = l >> 4, l15 = l & 15;
  int wm = w >> 1, wn = w & 1;

  // ---- staging source addresses (per-lane, pre-swizzled for A) ----
  // A round q in 0..3: rows w*32+q*8+(l>>3), 16B unit u=l&7 -> k16 = u^(row&7)
  int ar = w * 32 + (l >> 3);
  int acol = ((l & 7) ^ (l >> 3)) * 4;                    // k16^(row&7) inverted
  const float* ga = A + (size_t)(m0 + ar) * 1024 + t0 * 32 + acol;
  // B round q in 0..1: rows w*32+q*16+(l>>2), k-chunk (l&3)*8
  int br2 = w * 32 + (l >> 2);
  int bcol = (l & 3) * 8;
  const unsigned short* gb = Bb + (size_t)(n0 + br2) * 1024 + t0 * 32 + bcol;

  #define STAGE(bufi, tt)                                                  \
    {                                                                      \
      char* la = Asm[bufi] + w * 4096;                                     \
      char* lb = Bsm[bufi] + w * 2048;                                     \
      const float* gA = ga + (tt) * 32;                                    \
      const unsigned short* gB = gb + (tt) * 32;                           \
      gl_lds16(gA,         la);                                            \
      gl_lds16(gA + 8192,  la + 1024);                                     \
      gl_lds16(gA + 16384, la + 2048);                                     \
      gl_lds16(gA + 24576, la + 3072);                                     \
      gl_lds16(gB,         lb);                                            \
      gl_lds16(gB + 16384, lb + 1024);                                     \
    }

  f32x4 acc[4][4];
  #pragma unroll
  for (int i = 0; i < 4; i++)
    #pragma unroll
    for (int j = 0; j < 4; j++) acc[i][j] = (f32x4)(0.f);

  STAGE(0, 0);
  __syncthreads();

  for (int t = 0; t < nt; t++) {
    int buf = t & 1;
    if (t + 1 < nt) STAGE(buf ^ 1, t + 1);

    const char* Ab = Asm[buf];
    const char* Bf = Bsm[buf];
    short8 af[4], bfg[4];
    #pragma unroll
    for (int i = 0; i < 4; i++) {
      int row = wm * 64 + i * 16 + l15;
      const char* rb = Ab + row * 128;
      int u0 = ((2 * l4)     ^ (l15 & 7)) * 16;
      int u1 = ((2 * l4 + 1) ^ (l15 & 7)) * 16;
      float4 x = *(const float4*)(rb + u0);
      float4 y = *(const float4*)(rb + u1);
      union { short8 s; unsigned int u[4]; } fu;
      fu.u[0] = cvtpk(x.x, x.y);
      fu.u[1] = cvtpk(x.z, x.w);
      fu.u[2] = cvtpk(y.x, y.y);
      fu.u[3] = cvtpk(y.z, y.w);
      af[i] = fu.s;
    }
    #pragma unroll
    for (int j = 0; j < 4; j++) {
      int row = wn * 64 + j * 16 + l15;
      bfg[j] = *(const short8*)(Bf + row * 64 + l4 * 16);
    }
    #pragma unroll
    for (int i = 0; i < 4; i++)
      #pragma unroll
      for (int j = 0; j < 4; j++)
        acc[i][j] = mfma16(af[i], bfg[j], acc[i][j]);

    __syncthreads();
  }
  #undef STAGE

  if (MODE == 0) {
    float* o = of + (size_t)ksplit * 262144;
    #pragma unroll
    for (int i = 0; i < 4; i++)
      #pragma unroll
      for (int j = 0; j < 4; j++) {
        int n = n0 + wn * 64 + j * 16 + l15;
        #pragma unroll
        for (int r = 0; r < 4; r++) {
          int m = m0 + wm * 64 + i * 16 + l4 * 4 + r;
          o[(size_t)m * 1024 + n] = acc[i][j][r];
        }
      }
  } else {
    #pragma unroll
    for (int i = 0; i < 4; i++)
      #pragma unroll
      for (int j = 0; j < 4; j++) {
        int n = n0 + wn * 64 + j * 16 + l15;
        int kvv = n >> 6, d = n & 63;
        #pragma unroll
        for (int r = 0; r < 4; r++) {
          int m = m0 + wm * 64 + i * 16 + l4 * 4 + r;
          int bb = m >> 11, kk = m & 2047;
          unsigned short val = f2bf(acc[i][j][r]);
          if (kvv < 4)
            ok[((size_t)(bb * 4 + kvv) * 2048 + kk) * 64 + d] = val;           // (B,KV,K,D)
          else
            ov[((size_t)(bb * 4 + (kvv - 4)) * 64 + d) * 2048 + kk] = val;     // (B,KV,D,K)
        }
      }
  }
}

// ---------------------------------------------------------------------------
// Sum 4 K-split partials + RoPE + scale, write bf16 as (H, BIN, D)
// ---------------------------------------------------------------------------
__global__ __launch_bounds__(256) void rope_kernel(const float* __restrict__ qp,
                                                   const float* __restrict__ cosb,
                                                   const float* __restrict__ sinb,
                                                   unsigned short* __restrict__ qb) {
  int id = blockIdx.x * 256 + threadIdx.x;   // 262144
  int qrow = id >> 10, hd = id & 1023, hh = hd >> 6, d = hd & 63;
  int od = hh * 64 + ((d < 32) ? d + 32 : d - 32);
  float v = 0.f, o = 0.f;
  #pragma unroll
  for (int s4 = 0; s4 < 4; s4++) {
    v += qp[s4 * 262144 + qrow * 1024 + hd];
    o += qp[s4 * 262144 + qrow * 1024 + od];
  }
  if (d < 32) o = -o;
  float c = cosb[qrow * 64 + d];
  float s = sinb[qrow * 64 + d];
  float outv = (v * c + o * s) * 0.18033688011112042f;  // 0.125 * log2(e)
  qb[((size_t)hh * 256 + qrow) * 64 + d] = f2bf(outv);
}

// ---------------------------------------------------------------------------
// Flash attention, one block per (b, h, q-half). 4 waves x 32 q-rows.
// ---------------------------------------------------------------------------
__global__ __launch_bounds__(256) void attn_kernel(const unsigned short* __restrict__ qb,
                                                   const unsigned short* __restrict__ kb,
                                                   const unsigned short* __restrict__ vb,
                                                   const float* __restrict__ Wrp,
                                                   float* __restrict__ part) {
  __shared__ unsigned short Kt[2][4096];
  __shared__ unsigned short Vt[2][4096];
  __shared__ unsigned short Pl[4][2048];

  int bid = blockIdx.x;
  int vidx = (bid & 7) * 64 + (bid >> 3);     // XCD swizzle (512 = 8*64)
  int b = vidx >> 5, h = (vidx >> 1) & 15, qh = vidx & 1;
  int kvh = h >> 2;

  int tid = threadIdx.x;
  int w = tid >> 6, l = tid & 63;
  int l4 = l >> 4, l15 = l & 15;
  int q0 = qh * 128 + w * 32;

  const unsigned short* kg = kb + (size_t)(b * 4 + kvh) * 2048 * 64;
  const unsigned short* vg = vb + (size_t)(b * 4 + kvh) * 64 * 2048;

  short8 qf[2][2];
  #pragma unroll
  for (int fr = 0; fr < 2; fr++)
    #pragma unroll
    for (int ks = 0; ks < 2; ks++)
      qf[fr][ks] = *(const short8*)&qb[((size_t)h * 256 + q0 + fr * 16 + l15) * 64 + ks * 32 + l4 * 8];

  f32x4 O[2][4];
  #pragma unroll
  for (int fr = 0; fr < 2; fr++)
    #pragma unroll
    for (int fc = 0; fc < 4; fc++) O[fr][fc] = (f32x4)(0.f);
  float mrun[2][4], lrun[2][4];
  #pragma unroll
  for (int fr = 0; fr < 2; fr++)
    #pragma unroll
    for (int r = 0; r < 4; r++) { mrun[fr][r] = -1e30f; lrun[fr][r] = 0.f; }

  int srow = tid >> 2, sseg = tid & 3;
  int wb0 = srow * 128 + ((sseg * 32)      ^ ((srow & 7) << 4));
  int wb1 = srow * 128 + ((sseg * 32 + 16) ^ ((srow & 7) << 4));

  short8 k0r, k1r, v0r, v1r;
  {
    const unsigned short* ksrc = kg + srow * 64 + sseg * 16;
    const unsigned short* vsrc = vg + (size_t)srow * 2048 + sseg * 16;
    k0r = *(const short8*)(ksrc);     k1r = *(const short8*)(ksrc + 8);
    v0r = *(const short8*)(vsrc);     v1r = *(const short8*)(vsrc + 8);
    *(short8*)((char*)Kt[0] + wb0) = k0r;  *(short8*)((char*)Kt[0] + wb1) = k1r;
    *(short8*)((char*)Vt[0] + wb0) = v0r;  *(short8*)((char*)Vt[0] + wb1) = v1r;
  }

  for (int step = 0; step < 32; step++) {
    int buf = step & 1;
    __syncthreads();

    if (step + 1 < 32) {
      int kk = (step + 1) * 64;
      const unsigned short* ksrc = kg + (size_t)(kk + srow) * 64 + sseg * 16;
      const unsigned short* vsrc = vg + (size_t)srow * 2048 + kk + sseg * 16;
      k0r = *(const short8*)(ksrc);  k1r = *(const short8*)(ksrc + 8);
      v0r = *(const short8*)(vsrc);  v1r = *(const short8*)(vsrc + 8);
    }

    f32x4 S[2][4];
    #pragma unroll
    for (int fr = 0; fr < 2; fr++)
      #pragma unroll
      for (int fc = 0; fc < 4; fc++) S[fr][fc] = (f32x4)(0.f);
    #pragma unroll
    for (int ks = 0; ks < 2; ks++) {
      short8 kf[4];
      #pragma unroll
      for (int fc = 0; fc < 4; fc++) {
        int row = fc * 16 + l15;
        int byt = row * 128 + (((ks * 64) + l4 * 16) ^ ((row & 7) << 4));
        kf[fc] = *(const short8*)((char*)Kt[buf] + byt);
      }
      #pragma unroll
      for (int fr = 0; fr < 2; fr++)
        #pragma unroll
        for (int fc = 0; fc < 4; fc++)
          S[fr][fc] = mfma16(qf[fr][ks], kf[fc], S[fr][fc]);
    }

    #pragma unroll
    for (int fr = 0; fr < 2; fr++)
      #pragma unroll
      for (int r = 0; r < 4; r++) {
        float mx = fmaxf(fmaxf(S[fr][0][r], S[fr][1][r]), fmaxf(S[fr][2][r], S[fr][3][r]));
        mx = fmaxf(mx, __shfl_xor(mx, 1));
        mx = fmaxf(mx, __shfl_xor(mx, 2));
        mx = fmaxf(mx, __shfl_xor(mx, 4));
        mx = fmaxf(mx, __shfl_xor(mx, 8));
        float mold = mrun[fr][r];
        float mnew = fmaxf(mold, mx);
        float corr = exp2f(mold - mnew);
        mrun[fr][r] = mnew;
        float ls = lrun[fr][r] * corr;
        int row = fr * 16 + l4 * 4 + r;
        #pragma unroll
        for (int fc = 0; fc < 4; fc++) {
          float p = exp2f(S[fr][fc][r] - mnew);
          ls += p;
          int col = fc * 16 + l15;
          int byt = row * 128 + ((col * 2) ^ ((row & 7) << 4));
          *(unsigned short*)((char*)Pl[w] + byt) = f2bf(p);
          O[fr][fc][r] *= corr;
        }
        lrun[fr][r] = ls;
      }

    #pragma unroll
    for (int ks = 0; ks < 2; ks++) {
      short8 pf[2], vf[4];
      #pragma unroll
      for (int fr = 0; fr < 2; fr++) {
        int row = fr * 16 + l15;
        int byt = row * 128 + (((ks * 64) + l4 * 16) ^ ((row & 7) << 4));
        pf[fr] = *(const short8*)((char*)Pl[w] + byt);
      }
      #pragma unroll
      for (int fc = 0; fc < 4; fc++) {
        int row = fc * 16 + l15;
        int byt = row * 128 + (((ks * 64) + l4 * 16) ^ ((row & 7) << 4));
        vf[fc] = *(const short8*)((char*)Vt[buf] + byt);
      }
      #pragma unroll
      for (int fr = 0; fr < 2; fr++)
        #pragma unroll
        for (int fc = 0; fc < 4; fc++)
          O[fr][fc] = mfma16(pf[fr], vf[fc], O[fr][fc]);
    }

    if (step + 1 < 32) {
      int nb2 = buf ^ 1;
      *(short8*)((char*)Kt[nb2] + wb0) = k0r;  *(short8*)((char*)Kt[nb2] + wb1) = k1r;
      *(short8*)((char*)Vt[nb2] + wb0) = v0r;  *(short8*)((char*)Vt[nb2] + wb1) = v1r;
    }
  }

  float rinv[2][4];
  #pragma unroll
  for (int fr = 0; fr < 2; fr++)
    #pragma unroll
    for (int r = 0; r < 4; r++) {
      float ls = lrun[fr][r];
      ls += __shfl_xor(ls, 1);
      ls += __shfl_xor(ls, 2);
      ls += __shfl_xor(ls, 4);
      ls += __shfl_xor(ls, 8);
      rinv[fr][r] = 1.0f / ls;
    }

  float wc0[4], wc1[4];
  #pragma unroll
  for (int fc = 0; fc < 4; fc++) {
    wc0[fc] = Wrp[h * 64 + fc * 16 + l15];
    wc1[fc] = Wrp[1024 + h * 64 + fc * 16 + l15];
  }

  #pragma unroll
  for (int fr = 0; fr < 2; fr++)
    #pragma unroll
    for (int r = 0; r < 4; r++) {
      float a0 = 0.f, a1 = 0.f;
      #pragma unroll
      for (int fc = 0; fc < 4; fc++) {
        float o = O[fr][fc][r] * rinv[fr][r];
        a0 += o * wc0[fc];
        a1 += o * wc1[fc];
      }
      a0 += __shfl_xor(a0, 1); a0 += __shfl_xor(a0, 2);
      a0 += __shfl_xor(a0, 4); a0 += __shfl_xor(a0, 8);
      a1 += __shfl_xor(a1, 1); a1 += __shfl_xor(a1, 2);
      a1 += __shfl_xor(a1, 4); a1 += __shfl_xor(a1, 8);
      if (l15 == 0) {
        int qrow = q0 + fr * 16 + l4 * 4 + r;
        size_t base = ((size_t)(b * 16 + h) * 256 + qrow) * 2;
        part[base + 0] = a0;
        part[base + 1] = a1;
      }
    }
}

// ---------------------------------------------------------------------------
__global__ __launch_bounds__(256) void final_kernel(const float* __restrict__ part,
                                                    const float* __restrict__ br,
                                                    float* __restrict__ out) {
  int id = blockIdx.x * 256 + threadIdx.x;   // 8192
  int c = id & 1, q = (id >> 1) & 255, b = id >> 9;
  float s = br[c];
  #pragma unroll
  for (int hh = 0; hh < 16; hh++)
    s += part[(((size_t)(b * 16 + hh) * 256) + q) * 2 + c];
  out[id] = s;
}

// ---------------------------------------------------------------------------
extern "C" void kernel_launch(void* const* d_in, const int* in_sizes, int n_in,
                              void* d_out, int out_size, void* d_ws, size_t ws_size,
                              hipStream_t stream) {
  const float* h    = (const float*)d_in[0];
  const float* fcos = (const float*)d_in[1];
  const float* fsin = (const float*)d_in[2];
  const float* Wq   = (const float*)d_in[3];
  const float* Wk   = (const float*)d_in[4];
  const float* Wv   = (const float*)d_in[5];
  const float* Wo   = (const float*)d_in[6];
  const float* oq   = (const float*)d_in[7];
  const float* Wr   = (const float*)d_in[8];
  const float* br   = (const float*)d_in[9];
  float* out = (float*)d_out;

  char* ws = (char*)d_ws;
  unsigned short* kbuf = (unsigned short*)(ws);                 // 16 MB (B,KV,K,D) bf16
  unsigned short* vbuf = (unsigned short*)(ws + 16777216);      // 16 MB (B,KV,D,K) bf16
  float* qpart         = (float*)(ws + 33554432);               // 4 MB (4,256,1024)
  unsigned short* qbf  = (unsigned short*)(ws + 37748736);      // 0.5 MB (H,BIN,D)
  float* wpart         = (float*)(ws + 38273024);               // 128 KB
  float* Wrp           = (float*)(ws + 38404096);               // 8 KB
  float* apart         = (float*)(ws + 38412288);               // 512 KB (B,H,BIN,2)
  unsigned short* wqb  = (unsigned short*)(ws + 38936576);      // 2 MB (1024,1024)
  unsigned short* wkvb = (unsigned short*)(ws + 41033728);      // 1 MB (512,1024)

  cvtB_kernel<<<dim3(1536), dim3(256), 0, stream>>>(Wq, Wk, Wv, wqb, wkvb);
  wrp_partial<<<dim3(16), dim3(256), 0, stream>>>(Wr, Wo, wpart);
  wrp_reduce<<<dim3(8), dim3(256), 0, stream>>>(wpart, Wrp);
  gemm_f<0><<<dim3(64), dim3(256), 0, stream>>>(oq, wqb, nullptr, nullptr, qpart);
  rope_kernel<<<dim3(1024), dim3(256), 0, stream>>>(qpart, fcos, fsin, qbf);
  gemm_f<1><<<dim3(1024), dim3(256), 0, stream>>>(h, wkvb, kbuf, vbuf, nullptr);
  attn_kernel<<<dim3(512), dim3(256), 0, stream>>>(qbf, kbuf, vbuf, Wrp, apart);
  final_kernel<<<dim3(32), dim3(256), 0, stream>>>(apart, br, out);
}